// Round 12
// baseline (193.513 us; speedup 1.0000x reference)
//
#include <hip/hip_runtime.h>
#include <hip/hip_bf16.h>

#define NHEAD 8
#define CDIM 12
#define DMODEL 96
#define NBLK 128        // blocks in the counting-sort pass

__device__ __forceinline__ unsigned short f2bf(float f) {
    unsigned int u = __float_as_uint(f);
    unsigned int r = (u + 0x7fffu + ((u >> 16) & 1u)) >> 16;   // RNE
    return (unsigned short)r;
}

__device__ __forceinline__ float4 bf4_to_f4(ushort4 v) {
    float4 r;
    r.x = __uint_as_float((unsigned int)v.x << 16);
    r.y = __uint_as_float((unsigned int)v.y << 16);
    r.z = __uint_as_float((unsigned int)v.z << 16);
    r.w = __uint_as_float((unsigned int)v.w << 16);
    return r;
}

// ---------------- GEMM + fused att coeffs (v5: 2 nodes/lane, scalar W) -----
// H16[N,96](bf16) = X[N,K] @ W[K,96]. 256 thr = 4 waves per 128 nodes.
// Wave w owns cols [24w,24w+24) = heads {2w,2w+1}. Lane owns nodes
// (blk*128+lane) and (+64): 48 FMAs per k amortize W s_load latency and the
// X line-gather 2x vs v4. No LDS, no barriers, no atomics.
template<int K>
__global__ __launch_bounds__(256) void gemm_scalar_att(
    const float* __restrict__ X, const float* __restrict__ W,
    const float* __restrict__ att_s, const float* __restrict__ att_d,
    unsigned short* __restrict__ H16, float* __restrict__ a_s,
    float* __restrict__ a_d, int N)
{
    const int t = threadIdx.x;
    const int w = __builtin_amdgcn_readfirstlane(t >> 6);   // wave id 0..3
    const int lane = t & 63;
    const int c0 = __builtin_amdgcn_readfirstlane(w * 24);
    const int nodeA = blockIdx.x * 128 + lane;
    const int nodeB = nodeA + 64;
    const int ncA = (nodeA < N) ? nodeA : (N - 1);
    const int ncB = (nodeB < N) ? nodeB : (N - 1);
    const float* __restrict__ xrowA = X + (size_t)ncA * K;
    const float* __restrict__ xrowB = X + (size_t)ncB * K;

    float accA[24], accB[24];
#pragma unroll
    for (int c = 0; c < 24; ++c) { accA[c] = 0.f; accB[c] = 0.f; }

    float4 xvA = *(const float4*)(xrowA);
    float4 xvB = *(const float4*)(xrowB);
    for (int k4 = 0; k4 < K / 4; ++k4) {
        float4 nxA = make_float4(0.f, 0.f, 0.f, 0.f);
        float4 nxB = nxA;
        if (k4 + 1 < K / 4) {
            nxA = *(const float4*)(xrowA + 4 * (k4 + 1));
            nxB = *(const float4*)(xrowB + 4 * (k4 + 1));
        }
        const float xkA[4] = {xvA.x, xvA.y, xvA.z, xvA.w};
        const float xkB[4] = {xvB.x, xvB.y, xvB.z, xvB.w};
#pragma unroll
        for (int kk = 0; kk < 4; ++kk) {
            const float* __restrict__ wrow = W + (size_t)(k4 * 4 + kk) * 96 + c0;
#pragma unroll
            for (int c = 0; c < 24; ++c) {
                const float wv = wrow[c];
                accA[c] = fmaf(xkA[kk], wv, accA[c]);
                accB[c] = fmaf(xkB[kk], wv, accB[c]);
            }
        }
        xvA = nxA;
        xvB = nxB;
    }

    const int h0 = 2 * w;
#pragma unroll
    for (int half = 0; half < 2; ++half) {
        const int node = half ? nodeB : nodeA;
        const float* acc = half ? accB : accA;
        if (node < N) {
#pragma unroll
            for (int q = 0; q < 6; ++q) {
                ushort4 hv;
                hv.x = f2bf(acc[4 * q + 0]);
                hv.y = f2bf(acc[4 * q + 1]);
                hv.z = f2bf(acc[4 * q + 2]);
                hv.w = f2bf(acc[4 * q + 3]);
                *(ushort4*)(H16 + (size_t)node * 96 + c0 + 4 * q) = hv;
            }
            float s0 = 0.f, s1 = 0.f, d0 = 0.f, d1 = 0.f;
#pragma unroll
            for (int i = 0; i < 12; ++i) {
                s0 = fmaf(acc[i],      att_s[h0 * 12 + i],       s0);
                d0 = fmaf(acc[i],      att_d[h0 * 12 + i],       d0);
                s1 = fmaf(acc[12 + i], att_s[(h0 + 1) * 12 + i], s1);
                d1 = fmaf(acc[12 + i], att_d[(h0 + 1) * 12 + i], d1);
            }
            a_s[node * NHEAD + h0]     = s0;
            a_s[node * NHEAD + h0 + 1] = s1;
            a_d[node * NHEAD + h0]     = d0;
            a_d[node * NHEAD + h0 + 1] = d1;
        }
    }
}

// ---------------- CSR build: two-level counting sort, no global atomics ----
__global__ __launch_bounds__(1024) void hist2d_kernel(
    const int* __restrict__ dsti, int* __restrict__ hist2d,
    int E0, int Etot, int nbins)
{
    __shared__ int hist[1024];
    const int t = threadIdx.x, b = blockIdx.x;
    hist[t] = 0;
    __syncthreads();
    const int chunk = (Etot + NBLK - 1) / NBLK;
    const int e0 = b * chunk;
    const int e1 = (e0 + chunk < Etot) ? e0 + chunk : Etot;
    for (int e = e0 + t; e < e1; e += 1024) {
        int d = (e < E0) ? dsti[e] : e - E0;
        atomicAdd(&hist[d >> 6], 1);
    }
    __syncthreads();
    if (t < nbins) hist2d[(size_t)t * NBLK + b] = hist[t];
}

// records packed: (d<<16)|s  (both < 65536)
__global__ __launch_bounds__(1024) void place_kernel(
    const int* __restrict__ srci, const int* __restrict__ dsti,
    const int* __restrict__ sc2d, unsigned int* __restrict__ rec,
    int E0, int Etot)
{
    __shared__ int run[1024];
    const int t = threadIdx.x, b = blockIdx.x;
    run[t] = 0;
    __syncthreads();
    const int chunk = (Etot + NBLK - 1) / NBLK;
    const int e0 = b * chunk;
    const int e1 = (e0 + chunk < Etot) ? e0 + chunk : Etot;
    for (int e = e0 + t; e < e1; e += 1024) {
        int s, d;
        if (e < E0) { s = srci[e]; d = dsti[e]; }
        else        { s = d = e - E0; }
        int bin = d >> 6;
        int r = atomicAdd(&run[bin], 1);
        rec[(size_t)sc2d[bin * NBLK + b] + r] =
            ((unsigned int)d << 16) | (unsigned int)s;
    }
}

__global__ __launch_bounds__(256) void bucketDeg_kernel(
    const int* __restrict__ sc2d, const unsigned int* __restrict__ rec,
    int* __restrict__ deg, int N)
{
    __shared__ int deg64[64];
    const int t = threadIdx.x, b = blockIdx.x;
    if (t < 64) deg64[t] = 0;
    __syncthreads();
    const int r0 = sc2d[b * NBLK], r1 = sc2d[(b + 1) * NBLK];
    for (int i = r0 + t; i < r1; i += 256)
        atomicAdd(&deg64[(rec[i] >> 16) & 63], 1);
    __syncthreads();
    const int gn = b * 64 + t;
    if (t < 64 && gn < N) deg[gn] = deg64[t];
}

__global__ __launch_bounds__(256) void bucketC_kernel(
    const int* __restrict__ sc2d, const unsigned int* __restrict__ rec,
    const int* __restrict__ rowptr, int* __restrict__ col)
{
    __shared__ int run64[64];
    const int t = threadIdx.x, b = blockIdx.x;
    if (t < 64) run64[t] = 0;
    __syncthreads();
    const int r0 = sc2d[b * NBLK], r1 = sc2d[(b + 1) * NBLK];
    for (int i = r0 + t; i < r1; i += 256) {
        unsigned int v = rec[i];
        int d = (int)(v >> 16);
        int s = (int)(v & 0xFFFFu);
        int rank = atomicAdd(&run64[d & 63], 1);
        col[rowptr[d] + rank] = s;
    }
}

// ---------------- generic scan chain (exclusive) ----------------
__global__ __launch_bounds__(1024) void scan_block_kernel(
    const int* __restrict__ in, int* __restrict__ out,
    int* __restrict__ bsum, int n)
{
    __shared__ int sh[1024];
    int t = threadIdx.x, g = blockIdx.x * 1024 + t;
    int v = (g < n) ? in[g] : 0;
    sh[t] = v;
    __syncthreads();
    for (int off = 1; off < 1024; off <<= 1) {
        int add = (t >= off) ? sh[t - off] : 0;
        __syncthreads();
        sh[t] += add;
        __syncthreads();
    }
    if (g < n) out[g] = sh[t] - v;     // exclusive
    if (t == 1023) bsum[blockIdx.x] = sh[t];
}

__global__ void scan_bsum_kernel(int* bsum, int nb)
{
    if (threadIdx.x == 0) {
        int acc = 0;
        for (int i = 0; i < nb; ++i) { int v = bsum[i]; bsum[i] = acc; acc += v; }
    }
}

__global__ void scan_add_kernel(int* __restrict__ arr, const int* __restrict__ bsum,
                                int n, int total)
{
    int g = blockIdx.x * blockDim.x + threadIdx.x;
    if (g < n) arr[g] += bsum[g >> 10];
    if (g == 0) arr[n] = total;        // sentinel
}

// ---------------- edge pass (CSR): bf16 gather + fused softmax denom -------
__global__ __launch_bounds__(384) void edge2_vec_kernel(
    const int* __restrict__ rowptr, const int* __restrict__ col,
    const unsigned short* __restrict__ H16, const float* __restrict__ a_s,
    const float* __restrict__ a_d, const float* __restrict__ bias,
    float* __restrict__ out, int N)
{
    const int grp  = threadIdx.x / 24;      // 16 nodes/block
    const int lane = threadIdx.x % 24;      // 4-channel chunk
    const int d = blockIdx.x * 16 + grp;
    if (d >= N) return;
    const int hh = lane / 3;
    const float ad  = a_d[d * NHEAD + hh];
    const ushort4* __restrict__ Hc = (const ushort4*)H16;

    int j0 = rowptr[d], j1 = rowptr[d + 1];
    float4 acc = make_float4(0.f, 0.f, 0.f, 0.f);
    float den = 1e-16f;
    int j = j0;
    for (; j + 3 < j1; j += 4) {
        int s0 = col[j], s1 = col[j+1], s2 = col[j+2], s3 = col[j+3];
        float v0 = a_s[s0 * NHEAD + hh] + ad;
        float v1 = a_s[s1 * NHEAD + hh] + ad;
        float v2 = a_s[s2 * NHEAD + hh] + ad;
        float v3 = a_s[s3 * NHEAD + hh] + ad;
        ushort4 u0 = Hc[(size_t)s0 * 24 + lane];
        ushort4 u1 = Hc[(size_t)s1 * 24 + lane];
        ushort4 u2 = Hc[(size_t)s2 * 24 + lane];
        ushort4 u3 = Hc[(size_t)s3 * 24 + lane];
        v0 = v0 > 0.f ? v0 : 0.2f * v0;
        v1 = v1 > 0.f ? v1 : 0.2f * v1;
        v2 = v2 > 0.f ? v2 : 0.2f * v2;
        v3 = v3 > 0.f ? v3 : 0.2f * v3;
        float e0 = __expf(v0), e1 = __expf(v1), e2 = __expf(v2), e3 = __expf(v3);
        den += e0 + e1 + e2 + e3;
        float4 h0 = bf4_to_f4(u0), h1 = bf4_to_f4(u1);
        float4 h2 = bf4_to_f4(u2), h3 = bf4_to_f4(u3);
        acc.x = fmaf(e0, h0.x, acc.x); acc.y = fmaf(e0, h0.y, acc.y);
        acc.z = fmaf(e0, h0.z, acc.z); acc.w = fmaf(e0, h0.w, acc.w);
        acc.x = fmaf(e1, h1.x, acc.x); acc.y = fmaf(e1, h1.y, acc.y);
        acc.z = fmaf(e1, h1.z, acc.z); acc.w = fmaf(e1, h1.w, acc.w);
        acc.x = fmaf(e2, h2.x, acc.x); acc.y = fmaf(e2, h2.y, acc.y);
        acc.z = fmaf(e2, h2.z, acc.z); acc.w = fmaf(e2, h2.w, acc.w);
        acc.x = fmaf(e3, h3.x, acc.x); acc.y = fmaf(e3, h3.y, acc.y);
        acc.z = fmaf(e3, h3.z, acc.z); acc.w = fmaf(e3, h3.w, acc.w);
    }
    for (; j < j1; ++j) {
        int s = col[j];
        float v = a_s[s * NHEAD + hh] + ad;
        v = v > 0.f ? v : 0.2f * v;
        float ex = __expf(v);
        den += ex;
        float4 hv = bf4_to_f4(Hc[(size_t)s * 24 + lane]);
        acc.x = fmaf(ex, hv.x, acc.x); acc.y = fmaf(ex, hv.y, acc.y);
        acc.z = fmaf(ex, hv.z, acc.z); acc.w = fmaf(ex, hv.w, acc.w);
    }
    float inv = 1.0f / den;
    float4 bv = ((const float4*)bias)[lane];
    float4 o;
    o.x = fmaf(acc.x, inv, bv.x); o.y = fmaf(acc.y, inv, bv.y);
    o.z = fmaf(acc.z, inv, bv.z); o.w = fmaf(acc.w, inv, bv.w);
    o.x = o.x > 0.f ? o.x : 0.f;  o.y = o.y > 0.f ? o.y : 0.f;
    o.z = o.z > 0.f ? o.z : 0.f;  o.w = o.w > 0.f ? o.w : 0.f;
    ((float4*)out)[(size_t)d * 24 + lane] = o;
}

extern "C" void kernel_launch(void* const* d_in, const int* in_sizes, int n_in,
                              void* d_out, int out_size, void* d_ws, size_t ws_size,
                              hipStream_t stream) {
    const float* x   = (const float*)d_in[0];
    const int*   ei  = (const int*)d_in[1];
    const float* W1  = (const float*)d_in[2];
    const float* as1 = (const float*)d_in[3];
    const float* ad1 = (const float*)d_in[4];
    const float* b1  = (const float*)d_in[5];
    const float* W2  = (const float*)d_in[6];
    const float* as2 = (const float*)d_in[7];
    const float* ad2 = (const float*)d_in[8];
    const float* b2  = (const float*)d_in[9];

    const int N    = in_sizes[0] / 128;   // 50000
    const int E0   = in_sizes[1] / 2;     // 800000
    const int Etot = E0 + N;
    const int* srci = ei;
    const int* dsti = ei + E0;
    const int nbins = (N + 63) >> 6;      // 782
    const int M2    = nbins * NBLK;       // 100096

    // -------- workspace layout --------
    char* wsb = (char*)d_ws;
    unsigned short* H16 = (unsigned short*)wsb;  wsb += (size_t)N * DMODEL * 2;
    float* H1   = (float*)wsb;            wsb += (size_t)N * DMODEL * 4;
    float* AS   = (float*)wsb;            wsb += (size_t)N * NHEAD * 4;
    float* AD   = (float*)wsb;            wsb += (size_t)N * NHEAD * 4;
    int* HIST2D = (int*)wsb;              wsb += (size_t)M2 * 4;
    int* SC2D   = (int*)wsb;              wsb += (size_t)(M2 + 1) * 4;
    int* DEG    = (int*)wsb;              wsb += (size_t)N * 4;
    int* ROWPTR = (int*)wsb;              wsb += (size_t)(N + 1) * 4;
    int* BSUM   = (int*)wsb;              wsb += 256 * 4;
    int* COL    = (int*)wsb;              wsb += (size_t)Etot * 4;
    unsigned int* REC = (unsigned int*)wsb; wsb += (size_t)Etot * 4;
    float* OUT  = (float*)d_out;

    const int nb2       = (M2 + 1023) / 1024;   // 98
    const int nb_scan   = (N + 1023) / 1024;    // 49
    const int gemm_grid = (N + 127) / 128;      // 391
    const int e2_grid   = (N + 15) / 16;

    // -------- CSR build: counting sort, zero global atomics --------
    hist2d_kernel<<<NBLK, 1024, 0, stream>>>(dsti, HIST2D, E0, Etot, nbins);
    scan_block_kernel<<<nb2, 1024, 0, stream>>>(HIST2D, SC2D, BSUM, M2);
    scan_bsum_kernel<<<1, 64, 0, stream>>>(BSUM, nb2);
    scan_add_kernel<<<(M2 + 255) / 256, 256, 0, stream>>>(SC2D, BSUM, M2, Etot);
    place_kernel<<<NBLK, 1024, 0, stream>>>(srci, dsti, SC2D, REC, E0, Etot);
    bucketDeg_kernel<<<nbins, 256, 0, stream>>>(SC2D, REC, DEG, N);
    scan_block_kernel<<<nb_scan, 1024, 0, stream>>>(DEG, ROWPTR, BSUM, N);
    scan_bsum_kernel<<<1, 64, 0, stream>>>(BSUM, nb_scan);
    scan_add_kernel<<<(N + 255) / 256, 256, 0, stream>>>(ROWPTR, BSUM, N, Etot);
    bucketC_kernel<<<nbins, 256, 0, stream>>>(SC2D, REC, ROWPTR, COL);

    // -------- layer 1 --------
    gemm_scalar_att<128><<<gemm_grid, 256, 0, stream>>>(x, W1, as1, ad1, H16, AS, AD, N);
    edge2_vec_kernel<<<e2_grid, 384, 0, stream>>>(ROWPTR, COL, H16, AS, AD, b1, H1, N);

    // -------- layer 2 --------
    gemm_scalar_att<96><<<gemm_grid, 256, 0, stream>>>(H1, W2, as2, ad2, H16, AS, AD, N);
    edge2_vec_kernel<<<e2_grid, 384, 0, stream>>>(ROWPTR, COL, H16, AS, AD, b2, OUT, N);
}